// Round 6
// baseline (152.521 us; speedup 1.0000x reference)
//
#include <hip/hip_runtime.h>

#define W 512
#define H 512
#define PLANE (W * H)            // 262144
#define NPTS (32 * PLANE)        // 8388608 spatial points per channel
#define NBLK 512                 // 32 batches x 16 row-chunks

static constexpr float DT_INV = 100.0f;   // 1/DT
static constexpr float NU_C   = 0.001f;
// DX = 1.0 -> grad scale 0.5, laplacian scale 1.0

// Persistent strip walker. Block = (batch, 32-row chunk). 8 compute steps of
// 4 rows; LDS ring of 5 slots, each slot = one 4-row group of u and v
// (4*512*2*4 B = 16 KiB). Groups j=0..9 cover rows y0-4 .. y0+35 (periodic),
// so halos come from neighboring slots -- no intra-block halo re-fetch.
// DMA for group c+4 issued BEFORE computing step c => each barrier drains
// DMA that is ~4 compute-phases old => near-zero drain stall, memory engine
// stays busy across the whole kernel.
__global__ __launch_bounds__(256) void ns_loss_v6(
    const float* __restrict__ u_pred,
    const float* __restrict__ u_prev,
    float* __restrict__ partial)
{
    __shared__ float smem[5 * 4096];   // 81920 B -> 2 blocks/CU

    const int t    = threadIdx.x;
    const int lane = t & 63;
    const int wv   = t >> 6;

    // XCD-contiguous work assignment: XCD k owns work ids [64k, 64k+64)
    const int w  = ((blockIdx.x & 7) << 6) + (blockIdx.x >> 3);
    const int b  = w >> 4;            // batch 0..31
    const int y0 = (w & 15) << 5;     // chunk base row

    const float* u0 = u_pred + (size_t)b * (2 * PLANE);
    const float* v0 = u0 + PLANE;
    const float* q0 = u_prev + (size_t)b * (2 * PLANE);
    const float* q1 = q0 + PLANE;

    // Stage group j into slot j%5. Wave wv stages row r=wv of the group:
    // u half-rows then v half-rows, 4 x 1024 B DMA per wave.
    auto stage = [&](int j) {
        const int slot = j % 5;
        const int grow = (y0 + 508 + 4 * j + wv) & 511;   // y0-4+4j+wv mod 512
        float* base = smem + slot * 4096 + wv * 512;       // wave-uniform
        const float* gu = u0 + grow * W + lane * 4;
        const float* gv = v0 + grow * W + lane * 4;
        __builtin_amdgcn_global_load_lds(
            (const __attribute__((address_space(1))) void*)gu,
            (__attribute__((address_space(3))) void*)base, 16, 0, 0);
        __builtin_amdgcn_global_load_lds(
            (const __attribute__((address_space(1))) void*)(gu + 256),
            (__attribute__((address_space(3))) void*)(base + 256), 16, 0, 0);
        __builtin_amdgcn_global_load_lds(
            (const __attribute__((address_space(1))) void*)gv,
            (__attribute__((address_space(3))) void*)(base + 2048), 16, 0, 0);
        __builtin_amdgcn_global_load_lds(
            (const __attribute__((address_space(1))) void*)(gv + 256),
            (__attribute__((address_space(3))) void*)(base + 2048 + 256), 16, 0, 0);
    };

    // prologue: groups 0..3 in flight
    stage(0); stage(1); stage(2); stage(3);
    __syncthreads();   // drains prologue DMA

    const int r  = wv;                 // this wave's row within each step
    const int x0 = lane << 3;          // 8 consecutive x per lane
    const int lm = (lane + 63) & 63;
    const int lp = (lane + 1) & 63;

    float s_pde = 0.0f, s_div = 0.0f;

    for (int c = 0; c < 8; ++c) {
        if (c < 6) stage(c + 4);       // prefetch depth 4

        // prev-center rows straight from global (overlaps with LDS compute)
        const int y = (y0 + 4 * c + r) & 511;
        const float* pq0 = q0 + y * W + x0;
        const float* pq1 = q1 + y * W + x0;
        const float4 puL = *(const float4*)pq0;
        const float4 puH = *(const float4*)(pq0 + 4);
        const float4 pvL = *(const float4*)pq1;
        const float4 pvH = *(const float4*)(pq1 + 4);

        // LDS row bases (wave-uniform scalar math)
        const int e  = 4 * c + r + 4;          // center row id
        const float* Cu = smem + ((e >> 2) % 5) * 4096 + (e & 3) * 512;
        const float* Mu = smem + (((e - 1) >> 2) % 5) * 4096 + ((e - 1) & 3) * 512;
        const float* Pu = smem + (((e + 1) >> 2) % 5) * 4096 + ((e + 1) & 3) * 512;

        const float4 ucl = *(const float4*)(Cu + x0);
        const float4 uch = *(const float4*)(Cu + x0 + 4);
        const float4 uml = *(const float4*)(Mu + x0);
        const float4 umh = *(const float4*)(Mu + x0 + 4);
        const float4 upl = *(const float4*)(Pu + x0);
        const float4 uph = *(const float4*)(Pu + x0 + 4);
        const float4 vcl = *(const float4*)(Cu + 2048 + x0);
        const float4 vch = *(const float4*)(Cu + 2048 + x0 + 4);
        const float4 vml = *(const float4*)(Mu + 2048 + x0);
        const float4 vmh = *(const float4*)(Mu + 2048 + x0 + 4);
        const float4 vpl = *(const float4*)(Pu + 2048 + x0);
        const float4 vph = *(const float4*)(Pu + 2048 + x0 + 4);

        // x-neighbors across the 64-lane ring (512-periodic row fits exactly)
        const float uLm1 = __shfl(uch.w, lm);
        const float uRp1 = __shfl(ucl.x, lp);
        const float vLm1 = __shfl(vch.w, lm);
        const float vRp1 = __shfl(vcl.x, lp);

        const float ua[10] = {uLm1, ucl.x, ucl.y, ucl.z, ucl.w,
                              uch.x, uch.y, uch.z, uch.w, uRp1};
        const float va[10] = {vLm1, vcl.x, vcl.y, vcl.z, vcl.w,
                              vch.x, vch.y, vch.z, vch.w, vRp1};
        const float umA[8] = {uml.x, uml.y, uml.z, uml.w, umh.x, umh.y, umh.z, umh.w};
        const float upA[8] = {upl.x, upl.y, upl.z, upl.w, uph.x, uph.y, uph.z, uph.w};
        const float vmA[8] = {vml.x, vml.y, vml.z, vml.w, vmh.x, vmh.y, vmh.z, vmh.w};
        const float vpA[8] = {vpl.x, vpl.y, vpl.z, vpl.w, vph.x, vph.y, vph.z, vph.w};
        const float puA[8] = {puL.x, puL.y, puL.z, puL.w, puH.x, puH.y, puH.z, puH.w};
        const float pvA[8] = {pvL.x, pvL.y, pvL.z, pvL.w, pvH.x, pvH.y, pvH.z, pvH.w};

#pragma unroll
        for (int j = 0; j < 8; ++j) {
            const float u   = ua[j + 1];
            const float v   = va[j + 1];
            const float u_x = (ua[j + 2] - ua[j]) * 0.5f;
            const float v_x = (va[j + 2] - va[j]) * 0.5f;
            const float u_y = (upA[j] - umA[j]) * 0.5f;
            const float v_y = (vpA[j] - vmA[j]) * 0.5f;
            const float lap_u = upA[j] + umA[j] + ua[j + 2] + ua[j] - 4.0f * u;
            const float lap_v = vpA[j] + vmA[j] + va[j + 2] + va[j] - 4.0f * v;
            const float rx = (u - puA[j]) * DT_INV + u * u_x + v * u_y - NU_C * lap_u;
            const float ry = (v - pvA[j]) * DT_INV + u * v_x + v * v_y - NU_C * lap_v;
            const float dv = u_x + v_y;
            s_pde += rx * rx + ry * ry;
            s_div += dv * dv;
        }

        __syncthreads();   // WAR fence for ring reuse + drains in-flight DMA
    }

    // ---- reduction (smem reusable after final barrier) ----
#pragma unroll
    for (int off = 32; off > 0; off >>= 1) {
        s_pde += __shfl_down(s_pde, off);
        s_div += __shfl_down(s_div, off);
    }
    if (lane == 0) { smem[wv] = s_pde; smem[8 + wv] = s_div; }
    __syncthreads();
    if (t == 0) {
        partial[blockIdx.x]        = smem[0] + smem[1] + smem[2] + smem[3];
        partial[NBLK + blockIdx.x] = smem[8] + smem[9] + smem[10] + smem[11];
    }
}

__global__ __launch_bounds__(256) void ns_reduce(
    const float* __restrict__ partial,
    float* __restrict__ out)
{
    double sp = 0.0, sd = 0.0;
    for (int i = threadIdx.x; i < NBLK; i += 256) {
        sp += (double)partial[i];
        sd += (double)partial[NBLK + i];
    }
#pragma unroll
    for (int off = 32; off > 0; off >>= 1) {
        sp += __shfl_down(sp, off);
        sd += __shfl_down(sd, off);
    }
    __shared__ double ssp[4], ssd[4];
    const int lane = threadIdx.x & 63;
    const int wv   = threadIdx.x >> 6;
    if (lane == 0) { ssp[wv] = sp; ssd[wv] = sd; }
    __syncthreads();
    if (threadIdx.x == 0) {
        const double tp = ssp[0] + ssp[1] + ssp[2] + ssp[3];
        const double td = ssd[0] + ssd[1] + ssd[2] + ssd[3];
        const double inv = 1.0 / (double)NPTS;
        const double pde = tp * inv;
        const double dvl = td * inv;
        out[0] = (float)(pde + 0.1 * dvl);
        out[1] = (float)pde;
        out[2] = (float)dvl;
    }
}

extern "C" void kernel_launch(void* const* d_in, const int* in_sizes, int n_in,
                              void* d_out, int out_size, void* d_ws, size_t ws_size,
                              hipStream_t stream) {
    const float* u_pred = (const float*)d_in[0];
    const float* u_prev = (const float*)d_in[1];
    float* out = (float*)d_out;
    float* partial = (float*)d_ws;   // 2*NBLK floats = 4 KB

    ns_loss_v6<<<NBLK, 256, 0, stream>>>(u_pred, u_prev, partial);
    ns_reduce<<<1, 256, 0, stream>>>(partial, out);
}